// Round 1
// baseline (307.704 us; speedup 1.0000x reference)
//
#include <hip/hip_runtime.h>
#include <math.h>

#define N_ 128
#define I_ 256
#define O_ 256
#define P_ 16
#define OT 8      // o's per block
#define IT 16     // i's per block
#define SQRT_2PI 2.5066282746310002f
#define INV_SQRT_2PI 0.3989422804014327f

// grid: 32 o-tiles * 16 i-ranges = 512 blocks, 256 threads each.
// Each block: 8 o's, 16 i's, all 128 n. Accumulate in regs, atomicAdd at end.
__global__ __launch_bounds__(256, 2) void gp_fused(
    const float* __restrict__ x_mean, const float* __restrict__ x_var,
    const float* __restrict__ z_param, const float* __restrict__ h,
    const float* __restrict__ l_param, const float* __restrict__ s_param,
    const float* __restrict__ jitter_param, float* __restrict__ out)
{
    __shared__ float xm_s[N_][IT + 1];
    __shared__ float xv_s[N_][IT + 1];
    __shared__ float LinvS[OT][P_][P_];
    __shared__ float zS[OT][P_];
    __shared__ float wS[OT][P_];
    __shared__ float scS[OT][2];   // l2, s^2*l

    const int t = threadIdx.x;
    const int b = blockIdx.x;
    const int ot = b & 31;         // 32 o-tiles
    const int ir = b >> 5;         // 16 i-ranges
    const int o_base = ot * OT;
    const int i0 = ir * IT;

    // ---- stage x slice (coalesced float4 loads, once per block) ----
    for (int vidx = t; vidx < N_ * IT / 4; vidx += 256) {
        const int n = vidx >> 2, q = vidx & 3;
        const float4 xm4 = *(const float4*)(x_mean + n * I_ + i0 + q * 4);
        const float4 xv4 = *(const float4*)(x_var  + n * I_ + i0 + q * 4);
        xm_s[n][q*4+0] = xm4.x; xm_s[n][q*4+1] = xm4.y;
        xm_s[n][q*4+2] = xm4.z; xm_s[n][q*4+3] = xm4.w;
        xv_s[n][q*4+0] = xv4.x; xv_s[n][q*4+1] = xv4.y;
        xv_s[n][q*4+2] = xv4.z; xv_s[n][q*4+3] = xv4.w;
    }
    __syncthreads();

    float am[4] = {0.f, 0.f, 0.f, 0.f};
    float av[4] = {IT * 0.1f, IT * 0.1f, IT * 0.1f, IT * 0.1f}; // GLOBAL_JITTER per i

    const int ol = t >> 5;   // phase B: o_local (0..7), 32 threads each
    const int ln = t & 31;
    const int g  = t >> 4;   // phase A: group (0..7) for t<128
    const int p  = t & 15;   // phase A: lane-in-group

    for (int ii = 0; ii < IT; ++ii) {
        const int i = i0 + ii;

        // ================= Phase A: per-pair setup (threads 0..127) =========
        if (t < 128) {
            const int o  = o_base + g;
            const int io = i * O_ + o;
            const float l   = expf(l_param[io]) + 0.2f;
            const float s   = expf(s_param[io]) + 0.1f;
            const float jit = expf(jitter_param[io]) + 0.01f;
            const float l2 = l * l;
            const float inv2l2 = 0.5f / l2;
            const float cQ = INV_SQRT_2PI / l;
            const float noise = jit * jit / (s * s * l * SQRT_2PI);

            const float zp = tanhf(z_param[io * P_ + p]);

            // build row p of Q (row-per-lane)
            float a[P_];
            #pragma unroll
            for (int c = 0; c < P_; ++c) {
                const float zc = __shfl(zp, c, P_);
                const float d = zp - zc;
                a[c] = cQ * __expf(-d * d * inv2l2) + ((c == p) ? noise : 0.0f);
            }

            // in-register Cholesky (row-per-lane, static indices only)
            #pragma unroll
            for (int k = 0; k < P_; ++k) {
                const float akk = __shfl(a[k], k, P_);
                const float lkk = sqrtf(akk);
                const float inv_lkk = 1.0f / lkk;
                if (p == k)      a[k] = lkk;
                else if (p > k)  a[k] *= inv_lkk;
                const float lrk = a[k];   // own L[p][k] (valid for p>=k)
                #pragma unroll
                for (int c = k + 1; c < P_; ++c) {
                    const float lck = __shfl(a[k], c, P_);  // L[c][k]
                    if (p >= c) a[c] -= lrk * lck;
                }
            }

            // M = L^-1, column-per-lane (lane p computes column p)
            float x[P_];
            #pragma unroll
            for (int r = 0; r < P_; ++r) {
                const float lrr = __shfl(a[r], r, P_);
                float acc = (r == p) ? 1.0f : 0.0f;
                #pragma unroll
                for (int m = 0; m < r; ++m) {
                    const float lrm = __shfl(a[m], r, P_);  // L[r][m]
                    acc -= lrm * x[m];
                }
                x[r] = acc / lrr;   // exactly 0 for r < p
            }

            // w = M^T (M h)
            const float hc = h[io * P_ + p];
            float y[P_];
            #pragma unroll
            for (int r = 0; r < P_; ++r) y[r] = x[r] * hc;
            #pragma unroll
            for (int off = 8; off >= 1; off >>= 1) {
                #pragma unroll
                for (int r = 0; r < P_; ++r) y[r] += __shfl_xor(y[r], off, P_);
            }
            float wc = 0.f;
            #pragma unroll
            for (int r = 0; r < P_; ++r) wc += x[r] * y[r];

            // publish to LDS
            #pragma unroll
            for (int r = 0; r < P_; ++r) LinvS[g][r][p] = x[r];
            zS[g][p] = zp;
            wS[g][p] = wc;
            if (p == 0) { scS[g][0] = l2; scS[g][1] = s * s * l; }
        }
        __syncthreads();

        // ================= Phase B: per-site work (all 256 threads) =========
        {
            const float l2  = scS[ol][0];
            const float s2l = scS[ol][1];
            const float t4v = SQRT_2PI * s2l;
            float zr[P_], wr[P_];
            #pragma unroll
            for (int r = 0; r < P_; ++r) { zr[r] = zS[ol][r]; wr[r] = wS[ol][r]; }

            #pragma unroll
            for (int j = 0; j < 4; ++j) {
                const int n = ln + 32 * j;
                const float xm = xm_s[n][ii];
                const float xv = xv_s[n][ii];
                const float v = xv + l2;
                const float inv_v = 1.0f / v;
                const float h2v = 0.5f * inv_v;
                const float cc = rsqrtf(v) * INV_SQRT_2PI;

                float e[P_];
                float dm = 0.f;
                #pragma unroll
                for (int pp = 0; pp < P_; ++pp) {
                    const float d = xm - zr[pp];
                    e[pp] = __expf(-d * d * h2v);
                    dm += e[pp] * wr[pp];
                }

                float su = 0.f;
                #pragma unroll
                for (int r = 0; r < P_; ++r) {
                    float ur = 0.f;
                    #pragma unroll
                    for (int m = 0; m <= r; ++m) ur += LinvS[ol][r][m] * e[m];
                    su += ur * ur;
                }

                am[j] += cc * dm;
                const float t3 = s2l * rsqrtf(l2 + 2.f * xv);
                av[j] += t3 - t4v * (cc * cc) * su;
            }
        }
        __syncthreads();
    }

    // ---- accumulate into output (16 i-range blocks contend per address) ----
    const int o = o_base + ol;
    #pragma unroll
    for (int j = 0; j < 4; ++j) {
        const int n = ln + 32 * j;
        atomicAdd(out + n * O_ + o, am[j]);
        atomicAdd(out + N_ * O_ + n * O_ + o, av[j]);
    }
}

extern "C" void kernel_launch(void* const* d_in, const int* in_sizes, int n_in,
                              void* d_out, int out_size, void* d_ws, size_t ws_size,
                              hipStream_t stream) {
    const float* x_mean = (const float*)d_in[0];
    const float* x_var  = (const float*)d_in[1];
    const float* z_param = (const float*)d_in[2];
    const float* h       = (const float*)d_in[3];
    const float* l_param = (const float*)d_in[4];
    const float* s_param = (const float*)d_in[5];
    const float* jitter_param = (const float*)d_in[6];
    float* out = (float*)d_out;

    hipMemsetAsync(d_out, 0, (size_t)out_size * sizeof(float), stream);
    gp_fused<<<dim3(512), dim3(256), 0, stream>>>(
        x_mean, x_var, z_param, h, l_param, s_param, jitter_param, out);
}